// Round 2
// baseline (745.895 us; speedup 1.0000x reference)
//
#include <hip/hip_runtime.h>
#include <hip/hip_bf16.h>

#define NEG_SLOPE 0.2f

using bf16 = __hip_bfloat16;

__device__ __forceinline__ float tof(bf16 v) { return __bfloat162float(v); }
__device__ __forceinline__ float tof(float v) { return v; }
__device__ __forceinline__ void store_val(bf16* p, float v) { *p = __float2bfloat16(v); }
__device__ __forceinline__ void store_val(float* p, float v) { *p = v; }

// load 8 consecutive elems of T as fp32 (16B for bf16, 32B for fp32)
template <typename T>
__device__ __forceinline__ void load8(const T* p, float* o) {
    if constexpr (sizeof(T) == 2) {
        uint4 raw = *(const uint4*)p;
        const bf16* h = (const bf16*)&raw;
#pragma unroll
        for (int k = 0; k < 8; ++k) o[k] = tof(h[k]);
    } else {
        float4 r0 = *(const float4*)p;
        float4 r1 = *(const float4*)(p + 4);
        o[0] = r0.x; o[1] = r0.y; o[2] = r0.z; o[3] = r0.w;
        o[4] = r1.x; o[5] = r1.y; o[6] = r1.z; o[7] = r1.w;
    }
}

// Stage NS rows of F elems into LDS (row stride FP, fp32) from self(1)+neigh(NS-1).
template <typename T, int F, int NS, int FP>
__device__ __forceinline__ void stage(float* xs, const T* self, const T* neigh, int tid) {
    constexpr int V = 16 / sizeof(T);   // elems per 16B load (8 bf16 / 4 f32)
    constexpr int TOT = NS * F / V;
    for (int i = tid; i < TOT; i += 256) {
        int e = i * V;
        int s = e / F, f = e % F;
        const T* src = (s == 0) ? (self + f) : (neigh + (size_t)(s - 1) * F + f);
        uint4 raw = *(const uint4*)src;    // 16B coalesced
        const T* hv = (const T*)&raw;
        float* dst = &xs[s * FP + f];
#pragma unroll
        for (int k = 0; k < V; ++k) dst[k] = tof(hv[k]);
    }
}

// ---- wave-parallel logits + leaky_relu + softmax --------------------------
// Thread map: tid = half*128 + grp*32 + u. Lane u<NS: neighbor logit for
// sample u (row u; row 0 = self-as-sample). Lane u==NS: self logit (a_self).
// Each thread does an F/2 partial dot; halves combined via LDS; softmax via
// shfl over the 32-lane group. Result: attnT[s][h] (float4-readable rows).
template <typename T, int F, int NS, int FP>
__device__ __forceinline__ void attention2(const float* xs, const T* a_self,
                                           const T* a_neigh, float (*attnT)[4],
                                           float* part, int tid) {
    const int half = tid >> 7;          // 0..1 (f-half)
    const int grp  = (tid >> 5) & 3;    // head
    const int u    = tid & 31;          // sample (or NS = self-logit)
    float val = 0.f;
    if (u <= NS) {
        const T* a = ((u < NS) ? a_neigh : a_self) + (size_t)grp * F;
        const float* xrow = xs + (size_t)(u < NS ? u : 0) * FP;
        const int f0 = half * (F / 2);
        float s0 = 0.f, s1 = 0.f, s2 = 0.f, s3 = 0.f;
        float s4 = 0.f, s5 = 0.f, s6 = 0.f, s7 = 0.f;
#pragma unroll 2
        for (int f = f0; f < f0 + F / 2; f += 8) {
            float av[8];
            load8(a + f, av);
            float4 x0 = *(const float4*)(xrow + f);
            float4 x1 = *(const float4*)(xrow + f + 4);
            s0 += x0.x * av[0]; s1 += x0.y * av[1];
            s2 += x0.z * av[2]; s3 += x0.w * av[3];
            s4 += x1.x * av[4]; s5 += x1.y * av[5];
            s6 += x1.z * av[6]; s7 += x1.w * av[7];
        }
        val = ((s0 + s1) + (s2 + s3)) + ((s4 + s5) + (s6 + s7));
    }
    part[tid] = val;
    __syncthreads();
    if (half == 0) {
        float v = part[tid] + part[tid + 128];   // full logit
        float ls = __shfl(v, NS, 32);            // broadcast self logit in group
        float x = -1e30f;
        if (u < NS) {
            float t = ls + v;
            x = (t > 0.f) ? t : NEG_SLOPE * t;
        }
        float m = x;
#pragma unroll
        for (int off = 16; off; off >>= 1) m = fmaxf(m, __shfl_xor(m, off, 32));
        float e = (u < NS) ? __expf(x - m) : 0.f;
        float s = e;
#pragma unroll
        for (int off = 16; off; off >>= 1) s += __shfl_xor(s, off, 32);
        if (u < NS) attnT[u][grp] = e / s;
    }
    __syncthreads();
}

// xbar[h*F + f] = sum_s attnT[s][h] * xs[s][f]   (f = tid, tid+256, ...)
template <int F, int NS, int FP>
__device__ __forceinline__ void aggregate2(const float* xs, const float (*attnT)[4],
                                           float* xbar, int tid) {
    constexpr int FCH = F / 256;
    float acc[4][FCH];
#pragma unroll
    for (int h = 0; h < 4; ++h)
#pragma unroll
        for (int c = 0; c < FCH; ++c) acc[h][c] = 0.f;
#pragma unroll
    for (int s = 0; s < NS; ++s) {
        float4 w = *(const float4*)attnT[s];     // one b128 per sample
#pragma unroll
        for (int c = 0; c < FCH; ++c) {
            float xv = xs[(size_t)s * FP + tid + c * 256];
            acc[0][c] += w.x * xv;
            acc[1][c] += w.y * xv;
            acc[2][c] += w.z * xv;
            acc[3][c] += w.w * xv;
        }
    }
#pragma unroll
    for (int c = 0; c < FCH; ++c)
#pragma unroll
        for (int h = 0; h < 4; ++h)
            xbar[h * F + tid + c * 256] = acc[h][c];
}

// ---- kernel-A transform: d-ownership, vectorized w loads -------------------
// tid = cb*4 + g; cb: h = cb>>4, d0 = (cb&15)*8. Thread owns 8 consecutive d
// for batch-copy g. w loads: 16B, wave-dedup'd across the 4 g-lanes. xbar
// g-stride padded to 1028 floats -> conflict-free broadcast b32 reads.
template <typename T, int G>
__device__ __forceinline__ void transformA(const float* xbar, const T* w,
                                           float* wsout, int b0, int node, int tid) {
    static_assert(G == 4, "transformA assumes G==4");
    const int g  = tid & 3;
    const int cb = tid >> 2;
    const int h  = cb >> 4;
    const int d0 = (cb & 15) * 8;
    const T* wp = w + ((size_t)h * 256) * 128 + d0;
    const float* xb = xbar + g * 1028 + h * 256;
    float acc[8];
#pragma unroll
    for (int k = 0; k < 8; ++k) acc[k] = 0.f;
#pragma unroll 4
    for (int f = 0; f < 256; ++f) {
        float wv[8];
        load8(wp + (size_t)f * 128, wv);
        float xv = xb[f];
#pragma unroll
        for (int k = 0; k < 8; ++k) acc[k] += xv * wv[k];
    }
    float* o = wsout + ((size_t)(b0 + g) * 11 + node) * 512 + h * 128 + d0;
    *(float4*)(o + 0) = make_float4(acc[0], acc[1], acc[2], acc[3]);
    *(float4*)(o + 4) = make_float4(acc[4], acc[5], acc[6], acc[7]);
}

// ---- root transform: F=512, 4-way f-split + LDS tree reduction -------------
// tid = cb*4 + fq; thread owns 8 d's of (h = cb>>4), f-quarter fq.
// red = scratch [4][64][8] floats (aliased over dead hs).
template <typename T>
__device__ __forceinline__ void transformR(const float* xbar, const T* w,
                                           float* red, float* hroot, int tid) {
    const int fq = tid & 3;
    const int cb = tid >> 2;
    const int h  = cb >> 4;
    const int d0 = (cb & 15) * 8;
    const T* wp = w + ((size_t)h * 512) * 128 + d0;
    const float* xb = xbar + h * 512 + fq * 128;
    float acc[8];
#pragma unroll
    for (int k = 0; k < 8; ++k) acc[k] = 0.f;
#pragma unroll 4
    for (int i = 0; i < 128; ++i) {
        float wv[8];
        load8(wp + (size_t)(fq * 128 + i) * 128, wv);
        float xv = xb[i];
#pragma unroll
        for (int k = 0; k < 8; ++k) acc[k] += xv * wv[k];
    }
    float* r = red + ((size_t)fq * 64 + cb) * 8;
    *(float4*)(r + 0) = make_float4(acc[0], acc[1], acc[2], acc[3]);
    *(float4*)(r + 4) = make_float4(acc[4], acc[5], acc[6], acc[7]);
    __syncthreads();
    if (tid < 64) {
        float s[8] = {0.f, 0.f, 0.f, 0.f, 0.f, 0.f, 0.f, 0.f};
#pragma unroll
        for (int q = 0; q < 4; ++q) {
            const float* rr = red + ((size_t)q * 64 + tid) * 8;
            float4 p0 = *(const float4*)rr;
            float4 p1 = *(const float4*)(rr + 4);
            s[0] += p0.x; s[1] += p0.y; s[2] += p0.z; s[3] += p0.w;
            s[4] += p1.x; s[5] += p1.y; s[6] += p1.z; s[7] += p1.w;
        }
        float* o = hroot + tid * 8;
        *(float4*)(o + 0) = make_float4(s[0], s[1], s[2], s[3]);
        *(float4*)(o + 4) = make_float4(s[4], s[5], s[6], s[7]);
    }
    __syncthreads();
}

// ---- final projection: 256 outs, 8-way f-split + LDS reduction -------------
// tid = fq*32 + jb; thread owns 8 j's, f-chunk of 64. red = [8][32][8].
template <typename T>
__device__ __forceinline__ void projection2(const float* hroot, const T* fcw,
                                            T* outp, float* red, int tid) {
    const int fq = tid >> 5;
    const int jb = tid & 31;
    const int j0 = jb * 8;
    float acc[8];
#pragma unroll
    for (int k = 0; k < 8; ++k) acc[k] = 0.f;
#pragma unroll 4
    for (int i = 0; i < 64; ++i) {
        int f = fq * 64 + i;
        float wv[8];
        load8(fcw + (size_t)f * 256 + j0, wv);
        float xv = hroot[f];
#pragma unroll
        for (int k = 0; k < 8; ++k) acc[k] += xv * wv[k];
    }
    float* r = red + ((size_t)fq * 32 + jb) * 8;
    *(float4*)(r + 0) = make_float4(acc[0], acc[1], acc[2], acc[3]);
    *(float4*)(r + 4) = make_float4(acc[4], acc[5], acc[6], acc[7]);
    __syncthreads();
    if (tid < 32) {
        float s[8] = {0.f, 0.f, 0.f, 0.f, 0.f, 0.f, 0.f, 0.f};
#pragma unroll
        for (int q = 0; q < 8; ++q) {
            const float* rr = red + ((size_t)q * 32 + tid) * 8;
            float4 p0 = *(const float4*)rr;
            float4 p1 = *(const float4*)(rr + 4);
            s[0] += p0.x; s[1] += p0.y; s[2] += p0.z; s[3] += p0.w;
            s[4] += p1.x; s[5] += p1.y; s[6] += p1.z; s[7] += p1.w;
        }
#pragma unroll
        for (int k = 0; k < 8; ++k) store_val(outp + tid * 8 + k, s[k]);
    }
}

// Runtime dtype detection (unchanged, proven).
__device__ __forceinline__ int detect_fp32(const void* x0, int tid, int* flag_sm) {
    if (tid == 0) {
        const unsigned short* p = (const unsigned short*)x0;
        int f32 = 0;
        for (int i = 0; i < 128; ++i) {
            unsigned int u = ((unsigned int)p[i]) << 16;
            float v = __uint_as_float(u);
            if (!(fabsf(v) < 100.f)) f32 = 1;   // catches NaN too
        }
        *flag_sm = f32;
    }
    __syncthreads();
    return *flag_sm;
}

// ===================== Kernel A: all layer-0 node GATs ======================
template <typename T, int G>
__device__ __forceinline__ void l0_body2(
    const T* x0, const T* x1, const T* x2, const T* w0, const T* a0s,
    const T* a0n, float* wsout, float* xs, float* xbar, float (*attnT)[4],
    float* part, int b0, int node, int tid)
{
    for (int g = 0; g < G; ++g) {
        int b = b0 + g;
        if (node == 0) {
            stage<T, 256, 11, 260>(xs, x0 + (size_t)b * 256, x1 + (size_t)b * 2560, tid);
            __syncthreads();
            attention2<T, 256, 11, 260>(xs, a0s, a0n, attnT, part, tid);
            aggregate2<256, 11, 260>(xs, attnT, xbar + g * 1028, tid);
        } else {
            int p = node - 1;
            stage<T, 256, 26, 260>(xs, x1 + ((size_t)b * 10 + p) * 256,
                                   x2 + ((size_t)b * 250 + (size_t)p * 25) * 256, tid);
            __syncthreads();
            attention2<T, 256, 26, 260>(xs, a0s, a0n, attnT, part, tid);
            aggregate2<256, 26, 260>(xs, attnT, xbar + g * 1028, tid);
        }
        __syncthreads();   // xbar[g] complete; xs free for next g
    }
    transformA<T, G>(xbar, w0, wsout, b0, node, tid);
}

template <int G>
__global__ __launch_bounds__(256) void gat_l0(
    const void* x0, const void* x1, const void* x2, const void* w0,
    const void* a0s, const void* a0n, float* ws)
{
    const int node = blockIdx.x % 11;
    const int b0 = (blockIdx.x / 11) * G;
    const int tid = threadIdx.x;

    __shared__ __align__(16) float xs[26 * 260];      // 27040 B
    __shared__ __align__(16) float xbar[4 * 1028];    // 16448 B (g-stride padded)
    __shared__ __align__(16) float attnT[26][4];
    __shared__ float part[256];
    __shared__ int is_fp32;

    if (detect_fp32(x0, tid, &is_fp32)) {
        l0_body2<float, G>((const float*)x0, (const float*)x1, (const float*)x2,
                           (const float*)w0, (const float*)a0s, (const float*)a0n,
                           ws, xs, xbar, attnT, part, b0, node, tid);
    } else {
        l0_body2<bf16, G>((const bf16*)x0, (const bf16*)x1, (const bf16*)x2,
                          (const bf16*)w0, (const bf16*)a0s, (const bf16*)a0n,
                          ws, xs, xbar, attnT, part, b0, node, tid);
    }
}

// ============ Kernel B: layer 1 @ root + final projection (per batch) ========
template <typename T>
__device__ __forceinline__ void root_body2(
    const float* wsin, const T* w1, const T* a1s, const T* a1n, const T* fcw,
    T* out, float* hs, float* xbar, float* hroot, float (*attnT)[4],
    float* part, int b, int tid)
{
    // stage hs[11][512] (stride 516) from workspace, float4 loads
    for (int i = tid; i < 11 * 128; i += 256) {
        int e = i * 4;
        int s = e >> 9, f = e & 511;
        float4 v = *(const float4*)(wsin + ((size_t)b * 11 + s) * 512 + f);
        *(float4*)&hs[s * 516 + f] = v;
    }
    __syncthreads();
    attention2<T, 512, 11, 516>(hs, a1s, a1n, attnT, part, tid);
    aggregate2<512, 11, 516>(hs, attnT, xbar, tid);
    __syncthreads();
    // hs is dead from here -> reuse as reduction scratch
    transformR<T>(xbar, w1, hs, hroot, tid);
    projection2<T>(hroot, fcw, out + (size_t)b * 256, hs, tid);
}

__global__ __launch_bounds__(256) void gat_root(
    const void* x0, const float* ws, const void* w1, const void* a1s,
    const void* a1n, const void* fcw, void* out)
{
    const int b = blockIdx.x;
    const int tid = threadIdx.x;

    __shared__ __align__(16) float hs[11 * 516];     // 22704 B (also red scratch)
    __shared__ __align__(16) float xbar[4 * 512];    // 8192 B
    __shared__ __align__(16) float hroot[512];
    __shared__ __align__(16) float attnT[26][4];
    __shared__ float part[256];
    __shared__ int is_fp32;

    if (detect_fp32(x0, tid, &is_fp32)) {
        root_body2<float>(ws, (const float*)w1, (const float*)a1s,
                          (const float*)a1n, (const float*)fcw, (float*)out,
                          hs, xbar, hroot, attnT, part, b, tid);
    } else {
        root_body2<bf16>(ws, (const bf16*)w1, (const bf16*)a1s,
                         (const bf16*)a1n, (const bf16*)fcw, (bf16*)out,
                         hs, xbar, hroot, attnT, part, b, tid);
    }
}

// ================= Fallback: fully-fused single kernel (ws-less) ============
// Uses the original scalar transform; only runs if workspace is unavailable.
template <typename T, int F>
__device__ __forceinline__ void transform_o(const float* xbar, const T* w,
                                            float* dst, int tid) {
#pragma unroll
    for (int r = 0; r < 2; ++r) {
        int o = tid + r * 256;
        int h = o >> 7, d = o & 127;
        const T* wp = w + (size_t)h * F * 128 + d;
        const float* xb = xbar + (size_t)h * F;
        float a0 = 0.f, a1 = 0.f, a2 = 0.f, a3 = 0.f;
        for (int f = 0; f < F; f += 4) {
            a0 += xb[f + 0] * tof(wp[(size_t)(f + 0) * 128]);
            a1 += xb[f + 1] * tof(wp[(size_t)(f + 1) * 128]);
            a2 += xb[f + 2] * tof(wp[(size_t)(f + 2) * 128]);
            a3 += xb[f + 3] * tof(wp[(size_t)(f + 3) * 128]);
        }
        dst[o] = (a0 + a1) + (a2 + a3);
    }
}

template <typename T>
__device__ __forceinline__ void gat_body_fb(
    const T* x0, const T* x1, const T* x2, const T* w0, const T* a0s,
    const T* a0n, const T* w1, const T* a1s, const T* a1n, const T* fcw,
    T* out, float* xs, float* hs, float* xbar, float (*attnT)[4],
    float* part, float* hroot, int b, int tid)
{
    for (int p = 0; p < 10; ++p) {
        stage<T, 256, 26, 260>(xs, x1 + ((size_t)b * 10 + p) * 256,
                               x2 + ((size_t)b * 250 + (size_t)p * 25) * 256, tid);
        __syncthreads();
        attention2<T, 256, 26, 260>(xs, a0s, a0n, attnT, part, tid);
        aggregate2<256, 26, 260>(xs, attnT, xbar, tid);
        __syncthreads();
        transform_o<T, 256>(xbar, w0, &hs[(p + 1) * 516], tid);
        __syncthreads();
    }
    stage<T, 256, 11, 260>(xs, x0 + (size_t)b * 256, x1 + (size_t)b * 2560, tid);
    __syncthreads();
    attention2<T, 256, 11, 260>(xs, a0s, a0n, attnT, part, tid);
    aggregate2<256, 11, 260>(xs, attnT, xbar, tid);
    __syncthreads();
    transform_o<T, 256>(xbar, w0, &hs[0], tid);
    __syncthreads();
    attention2<T, 512, 11, 516>(hs, a1s, a1n, attnT, part, tid);
    aggregate2<512, 11, 516>(hs, attnT, xbar, tid);
    __syncthreads();
    transform_o<T, 512>(xbar, w1, hroot, tid);
    __syncthreads();
    const T* fp = fcw + tid;
    float a0 = 0.f, a1 = 0.f, a2 = 0.f, a3 = 0.f;
    for (int f = 0; f < 512; f += 4) {
        a0 += hroot[f + 0] * tof(fp[(size_t)(f + 0) * 256]);
        a1 += hroot[f + 1] * tof(fp[(size_t)(f + 1) * 256]);
        a2 += hroot[f + 2] * tof(fp[(size_t)(f + 2) * 256]);
        a3 += hroot[f + 3] * tof(fp[(size_t)(f + 3) * 256]);
    }
    store_val(&out[(size_t)b * 256 + tid], (a0 + a1) + (a2 + a3));
}

__global__ __launch_bounds__(256) void gat_fused(
    const void* x0, const void* x1, const void* x2, const void* w0,
    const void* a0s, const void* a0n, const void* w1, const void* a1s,
    const void* a1n, const void* fcw, void* out)
{
    const int b = blockIdx.x;
    const int tid = threadIdx.x;

    __shared__ __align__(16) float xs[26 * 260];
    __shared__ __align__(16) float hs[11 * 516];
    __shared__ __align__(16) float xbar[4 * 512];
    __shared__ __align__(16) float attnT[26][4];
    __shared__ float part[256];
    __shared__ __align__(16) float hroot[512];
    __shared__ int is_fp32;

    if (detect_fp32(x0, tid, &is_fp32)) {
        gat_body_fb<float>((const float*)x0, (const float*)x1, (const float*)x2,
                           (const float*)w0, (const float*)a0s, (const float*)a0n,
                           (const float*)w1, (const float*)a1s, (const float*)a1n,
                           (const float*)fcw, (float*)out,
                           xs, hs, xbar, attnT, part, hroot, b, tid);
    } else {
        gat_body_fb<bf16>((const bf16*)x0, (const bf16*)x1, (const bf16*)x2,
                          (const bf16*)w0, (const bf16*)a0s, (const bf16*)a0n,
                          (const bf16*)w1, (const bf16*)a1s, (const bf16*)a1n,
                          (const bf16*)fcw, (bf16*)out,
                          xs, hs, xbar, attnT, part, hroot, b, tid);
    }
}

extern "C" void kernel_launch(void* const* d_in, const int* in_sizes, int n_in,
                              void* d_out, int out_size, void* d_ws, size_t ws_size,
                              hipStream_t stream) {
    const int B = in_sizes[0] / 256;  // 1024
    constexpr int G = 4;              // batches per block in kernel A
    const size_t ws_need = (size_t)B * 11 * 512 * sizeof(float);  // 23.1 MB

    if (d_ws && ws_size >= ws_need && (B % G) == 0) {
        float* ws = (float*)d_ws;
        gat_l0<G><<<(B / G) * 11, 256, 0, stream>>>(
            d_in[0], d_in[1], d_in[2], d_in[3], d_in[4], d_in[5], ws);
        gat_root<<<B, 256, 0, stream>>>(
            d_in[0], ws, d_in[6], d_in[7], d_in[8], d_in[9], d_out);
    } else {
        gat_fused<<<B, 256, 0, stream>>>(d_in[0], d_in[1], d_in[2], d_in[3],
                                         d_in[4], d_in[5], d_in[6], d_in[7],
                                         d_in[8], d_in[9], d_out);
    }
}

// Round 3
// 591.869 us; speedup vs baseline: 1.2602x; 1.2602x over previous
//
#include <hip/hip_runtime.h>
#include <hip/hip_bf16.h>

#define NEG_SLOPE 0.2f

using bf16 = __hip_bfloat16;

__device__ __forceinline__ float tof(bf16 v) { return __bfloat162float(v); }
__device__ __forceinline__ float tof(float v) { return v; }
__device__ __forceinline__ void store_val(bf16* p, float v) { *p = __float2bfloat16(v); }
__device__ __forceinline__ void store_val(float* p, float v) { *p = v; }

// load 8 consecutive elems of T as fp32 (16B for bf16, 32B for fp32)
template <typename T>
__device__ __forceinline__ void load8(const T* p, float* o) {
    if constexpr (sizeof(T) == 2) {
        uint4 raw = *(const uint4*)p;
        const bf16* h = (const bf16*)&raw;
#pragma unroll
        for (int k = 0; k < 8; ++k) o[k] = tof(h[k]);
    } else {
        float4 r0 = *(const float4*)p;
        float4 r1 = *(const float4*)(p + 4);
        o[0] = r0.x; o[1] = r0.y; o[2] = r0.z; o[3] = r0.w;
        o[4] = r1.x; o[5] = r1.y; o[6] = r1.z; o[7] = r1.w;
    }
}

// Stage NS rows of F elems into LDS (row stride FP, fp32) from self(1)+neigh(NS-1).
template <typename T, int F, int NS, int FP>
__device__ __forceinline__ void stage(float* xs, const T* self, const T* neigh, int tid) {
    constexpr int V = 16 / sizeof(T);
    constexpr int TOT = NS * F / V;
    for (int i = tid; i < TOT; i += 256) {
        int e = i * V;
        int s = e / F, f = e % F;
        const T* src = (s == 0) ? (self + f) : (neigh + (size_t)(s - 1) * F + f);
        uint4 raw = *(const uint4*)src;
        const T* hv = (const T*)&raw;
        float* dst = &xs[s * FP + f];
#pragma unroll
        for (int k = 0; k < V; ++k) dst[k] = tof(hv[k]);
    }
}

// ---- wave-parallel logits + leaky_relu + softmax (validated round 2) ------
template <typename T, int F, int NS, int FP>
__device__ __forceinline__ void attention2(const float* xs, const T* a_self,
                                           const T* a_neigh, float (*attnT)[4],
                                           float* part, int tid) {
    const int half = tid >> 7;
    const int grp  = (tid >> 5) & 3;
    const int u    = tid & 31;
    float val = 0.f;
    if (u <= NS) {
        const T* a = ((u < NS) ? a_neigh : a_self) + (size_t)grp * F;
        const float* xrow = xs + (size_t)(u < NS ? u : 0) * FP;
        const int f0 = half * (F / 2);
        float s0 = 0.f, s1 = 0.f, s2 = 0.f, s3 = 0.f;
        float s4 = 0.f, s5 = 0.f, s6 = 0.f, s7 = 0.f;
#pragma unroll 2
        for (int f = f0; f < f0 + F / 2; f += 8) {
            float av[8];
            load8(a + f, av);
            float4 x0 = *(const float4*)(xrow + f);
            float4 x1 = *(const float4*)(xrow + f + 4);
            s0 += x0.x * av[0]; s1 += x0.y * av[1];
            s2 += x0.z * av[2]; s3 += x0.w * av[3];
            s4 += x1.x * av[4]; s5 += x1.y * av[5];
            s6 += x1.z * av[6]; s7 += x1.w * av[7];
        }
        val = ((s0 + s1) + (s2 + s3)) + ((s4 + s5) + (s6 + s7));
    }
    part[tid] = val;
    __syncthreads();
    if (half == 0) {
        float v = part[tid] + part[tid + 128];
        float ls = __shfl(v, NS, 32);
        float x = -1e30f;
        if (u < NS) {
            float t = ls + v;
            x = (t > 0.f) ? t : NEG_SLOPE * t;
        }
        float m = x;
#pragma unroll
        for (int off = 16; off; off >>= 1) m = fmaxf(m, __shfl_xor(m, off, 32));
        float e = (u < NS) ? __expf(x - m) : 0.f;
        float s = e;
#pragma unroll
        for (int off = 16; off; off >>= 1) s += __shfl_xor(s, off, 32);
        if (u < NS) attnT[u][grp] = e / s;
    }
    __syncthreads();
}

// Runtime dtype detection (proven).
__device__ __forceinline__ int detect_fp32(const void* x0, int tid, int* flag_sm) {
    if (tid == 0) {
        const unsigned short* p = (const unsigned short*)x0;
        int f32 = 0;
        for (int i = 0; i < 128; ++i) {
            unsigned int u = ((unsigned int)p[i]) << 16;
            float v = __uint_as_float(u);
            if (!(fabsf(v) < 100.f)) f32 = 1;
        }
        *flag_sm = f32;
    }
    __syncthreads();
    return *flag_sm;
}

// ===================== Phase A: aggregate level-0 ===========================
template <int NS>
__device__ __forceinline__ void agg_store(const float* xs, const float (*attnT)[4],
                                          float* dst, int tid) {
    float a0 = 0.f, a1 = 0.f, a2 = 0.f, a3 = 0.f;
#pragma unroll
    for (int s = 0; s < NS; ++s) {
        float4 w = *(const float4*)attnT[s];
        float xv = xs[(size_t)s * 260 + tid];
        a0 += w.x * xv; a1 += w.y * xv; a2 += w.z * xv; a3 += w.w * xv;
    }
    dst[tid] = a0; dst[256 + tid] = a1; dst[512 + tid] = a2; dst[768 + tid] = a3;
}

template <typename T>
__device__ __forceinline__ void agg0_body(
    const T* x0, const T* x1, const T* x2, const T* a0s, const T* a0n,
    float* xbar0, float* xs, float (*attnT)[4], float* part,
    int b, int node, int tid)
{
    float* dst = xbar0 + (size_t)(b * 11 + node) * 1024;
    if (node == 0) {
        stage<T, 256, 11, 260>(xs, x0 + (size_t)b * 256, x1 + (size_t)b * 2560, tid);
        __syncthreads();
        attention2<T, 256, 11, 260>(xs, a0s, a0n, attnT, part, tid);
        agg_store<11>(xs, attnT, dst, tid);
    } else {
        int p = node - 1;
        stage<T, 256, 26, 260>(xs, x1 + ((size_t)b * 10 + p) * 256,
                               x2 + ((size_t)b * 250 + (size_t)p * 25) * 256, tid);
        __syncthreads();
        attention2<T, 256, 26, 260>(xs, a0s, a0n, attnT, part, tid);
        agg_store<26>(xs, attnT, dst, tid);
    }
}

__global__ __launch_bounds__(256) void gat_agg0(
    const void* x0, const void* x1, const void* x2,
    const void* a0s, const void* a0n, float* xbar0)
{
    const int node = blockIdx.x % 11;
    const int b = blockIdx.x / 11;
    const int tid = threadIdx.x;
    __shared__ __align__(16) float xs[26 * 260];
    __shared__ __align__(16) float attnT[26][4];
    __shared__ float part[256];
    __shared__ int is_fp32;
    if (detect_fp32(x0, tid, &is_fp32))
        agg0_body<float>((const float*)x0, (const float*)x1, (const float*)x2,
                         (const float*)a0s, (const float*)a0n, xbar0,
                         xs, attnT, part, b, node, tid);
    else
        agg0_body<bf16>((const bf16*)x0, (const bf16*)x1, (const bf16*)x2,
                        (const bf16*)a0s, (const bf16*)a0n, xbar0,
                        xs, attnT, part, b, node, tid);
}

// ===================== Tiled GEMM (transform / projection) ==================
// Y[n][ht*OCOLM + d] = sum_k X[n][ht*XCOLM + k] * W[ht*WHOFF + k*WROW + d]
// Block tile: MT rows x 128 cols. 256 threads: tx(16) owns 8 d, ty(16) owns
// MR=MT/16 rows. K staged in LDS chunks of 32 (xbt pad 36, wt pad 132).
template <typename T, typename OT, int MT, int KTOT, int XROW, int XCOLM,
          int WHOFF, int WROW, int OROW, int OCOLM, int NHT>
__device__ __forceinline__ void gemm_body(
    const float* __restrict__ X, const T* __restrict__ W, OT* __restrict__ Y,
    float* xbt, float* wt, int bid, int tid)
{
    constexpr int KC = 32;
    constexpr int MR = MT / 16;
    const int ht = bid % NHT;
    const int mt = bid / NHT;
    const int n0 = mt * MT;
    const int tx = tid & 15;
    const int ty = tid >> 4;

    const float* Xb = X + (size_t)n0 * XROW + (size_t)ht * XCOLM;
    const T* Wb = W + (size_t)ht * WHOFF;

    float acc[MR][8];
#pragma unroll
    for (int m = 0; m < MR; ++m)
#pragma unroll
        for (int d = 0; d < 8; ++d) acc[m][d] = 0.f;

    for (int kc = 0; kc < KTOT; kc += KC) {
        __syncthreads();
        for (int i = tid; i < MT * KC / 4; i += 256) {
            int r = i >> 3;            // KC/4 = 8 float4 per row
            int c = (i & 7) << 2;
            *(float4*)&xbt[r * 36 + c] = *(const float4*)(Xb + (size_t)r * XROW + kc + c);
        }
        for (int i = tid; i < KC * 16; i += 256) {
            int r = i >> 4, c = (i & 15) << 3;
            float tmp[8];
            load8(Wb + (size_t)(kc + r) * WROW + c, tmp);
            *(float4*)&wt[r * 132 + c] = make_float4(tmp[0], tmp[1], tmp[2], tmp[3]);
            *(float4*)&wt[r * 132 + c + 4] = make_float4(tmp[4], tmp[5], tmp[6], tmp[7]);
        }
        __syncthreads();
#pragma unroll 2
        for (int k = 0; k < KC; k += 4) {
            float4 xv[MR];
#pragma unroll
            for (int m = 0; m < MR; ++m)
                xv[m] = *(const float4*)&xbt[(ty * MR + m) * 36 + k];
#pragma unroll
            for (int kk = 0; kk < 4; ++kk) {
                float wv[8];
                *(float4*)&wv[0] = *(const float4*)&wt[(k + kk) * 132 + tx * 8];
                *(float4*)&wv[4] = *(const float4*)&wt[(k + kk) * 132 + tx * 8 + 4];
#pragma unroll
                for (int m = 0; m < MR; ++m) {
                    float xsv = (kk == 0) ? xv[m].x : (kk == 1) ? xv[m].y
                              : (kk == 2) ? xv[m].z : xv[m].w;
#pragma unroll
                    for (int d = 0; d < 8; ++d) acc[m][d] += xsv * wv[d];
                }
            }
        }
    }
#pragma unroll
    for (int m = 0; m < MR; ++m) {
        OT* yp = Y + (size_t)(n0 + ty * MR + m) * OROW + ht * OCOLM + tx * 8;
        if constexpr (sizeof(OT) == 4) {
            *(float4*)(yp + 0) = make_float4(acc[m][0], acc[m][1], acc[m][2], acc[m][3]);
            *(float4*)(yp + 4) = make_float4(acc[m][4], acc[m][5], acc[m][6], acc[m][7]);
        } else {
#pragma unroll
            for (int d = 0; d < 8; ++d) store_val(yp + d, acc[m][d]);
        }
    }
}

template <int MT, int KTOT, int XROW, int XCOLM, int WHOFF, int WROW,
          int OROW, int OCOLM, int NHT, bool OUT_T>
__global__ __launch_bounds__(256) void gat_gemm(
    const void* x0, const float* X, const void* W, void* Y)
{
    __shared__ __align__(16) float xbt[MT * 36];
    __shared__ __align__(16) float wt[32 * 132];
    __shared__ int is_fp32;
    const int tid = threadIdx.x;
    if (detect_fp32(x0, tid, &is_fp32)) {
        gemm_body<float, float, MT, KTOT, XROW, XCOLM, WHOFF, WROW, OROW, OCOLM, NHT>(
            X, (const float*)W, (float*)Y, xbt, wt, blockIdx.x, tid);
    } else {
        if constexpr (OUT_T)
            gemm_body<bf16, bf16, MT, KTOT, XROW, XCOLM, WHOFF, WROW, OROW, OCOLM, NHT>(
                X, (const bf16*)W, (bf16*)Y, xbt, wt, blockIdx.x, tid);
        else
            gemm_body<bf16, float, MT, KTOT, XROW, XCOLM, WHOFF, WROW, OROW, OCOLM, NHT>(
                X, (const bf16*)W, (float*)Y, xbt, wt, blockIdx.x, tid);
    }
}

// ===================== Phase C1: aggregate level-1 ==========================
template <typename T>
__device__ __forceinline__ void agg1_body(
    const float* hsws, const T* a1s, const T* a1n, float* xbar1,
    float* hs, float (*attnT)[4], float* part, int b, int tid)
{
    for (int i = tid; i < 11 * 128; i += 256) {
        int s = i >> 7, f = (i & 127) << 2;
        *(float4*)&hs[s * 516 + f] = *(const float4*)(hsws + ((size_t)b * 11 + s) * 512 + f);
    }
    __syncthreads();
    attention2<T, 512, 11, 516>(hs, a1s, a1n, attnT, part, tid);
    float acc[4][2] = {{0.f,0.f},{0.f,0.f},{0.f,0.f},{0.f,0.f}};
#pragma unroll
    for (int s = 0; s < 11; ++s) {
        float4 w = *(const float4*)attnT[s];
        float x0v = hs[s * 516 + tid];
        float x1v = hs[s * 516 + tid + 256];
        acc[0][0] += w.x * x0v; acc[0][1] += w.x * x1v;
        acc[1][0] += w.y * x0v; acc[1][1] += w.y * x1v;
        acc[2][0] += w.z * x0v; acc[2][1] += w.z * x1v;
        acc[3][0] += w.w * x0v; acc[3][1] += w.w * x1v;
    }
    float* dst = xbar1 + (size_t)b * 2048;
#pragma unroll
    for (int h = 0; h < 4; ++h) {
        dst[h * 512 + tid] = acc[h][0];
        dst[h * 512 + tid + 256] = acc[h][1];
    }
}

__global__ __launch_bounds__(256) void gat_agg1(
    const void* x0, const float* hsws, const void* a1s, const void* a1n,
    float* xbar1)
{
    const int b = blockIdx.x;
    const int tid = threadIdx.x;
    __shared__ __align__(16) float hs[11 * 516];
    __shared__ __align__(16) float attnT[26][4];
    __shared__ float part[256];
    __shared__ int is_fp32;
    if (detect_fp32(x0, tid, &is_fp32))
        agg1_body<float>(hsws, (const float*)a1s, (const float*)a1n, xbar1,
                         hs, attnT, part, b, tid);
    else
        agg1_body<bf16>(hsws, (const bf16*)a1s, (const bf16*)a1n, xbar1,
                        hs, attnT, part, b, tid);
}

// ================= Fallback helpers (round-2 path, validated) ===============
template <int F, int NS, int FP>
__device__ __forceinline__ void aggregate2(const float* xs, const float (*attnT)[4],
                                           float* xbar, int tid) {
    constexpr int FCH = F / 256;
    float acc[4][FCH];
#pragma unroll
    for (int h = 0; h < 4; ++h)
#pragma unroll
        for (int c = 0; c < FCH; ++c) acc[h][c] = 0.f;
#pragma unroll
    for (int s = 0; s < NS; ++s) {
        float4 w = *(const float4*)attnT[s];
#pragma unroll
        for (int c = 0; c < FCH; ++c) {
            float xv = xs[(size_t)s * FP + tid + c * 256];
            acc[0][c] += w.x * xv;
            acc[1][c] += w.y * xv;
            acc[2][c] += w.z * xv;
            acc[3][c] += w.w * xv;
        }
    }
#pragma unroll
    for (int c = 0; c < FCH; ++c)
#pragma unroll
        for (int h = 0; h < 4; ++h)
            xbar[h * F + tid + c * 256] = acc[h][c];
}

template <typename T, int G>
__device__ __forceinline__ void transformA(const float* xbar, const T* w,
                                           float* wsout, int b0, int node, int tid) {
    const int g  = tid & 3;
    const int cb = tid >> 2;
    const int h  = cb >> 4;
    const int d0 = (cb & 15) * 8;
    const T* wp = w + ((size_t)h * 256) * 128 + d0;
    const float* xb = xbar + g * 1028 + h * 256;
    float acc[8];
#pragma unroll
    for (int k = 0; k < 8; ++k) acc[k] = 0.f;
#pragma unroll 4
    for (int f = 0; f < 256; ++f) {
        float wv[8];
        load8(wp + (size_t)f * 128, wv);
        float xv = xb[f];
#pragma unroll
        for (int k = 0; k < 8; ++k) acc[k] += xv * wv[k];
    }
    float* o = wsout + ((size_t)(b0 + g) * 11 + node) * 512 + h * 128 + d0;
    *(float4*)(o + 0) = make_float4(acc[0], acc[1], acc[2], acc[3]);
    *(float4*)(o + 4) = make_float4(acc[4], acc[5], acc[6], acc[7]);
}

template <typename T>
__device__ __forceinline__ void transformR(const float* xbar, const T* w,
                                           float* red, float* hroot, int tid) {
    const int fq = tid & 3;
    const int cb = tid >> 2;
    const int h  = cb >> 4;
    const int d0 = (cb & 15) * 8;
    const T* wp = w + ((size_t)h * 512) * 128 + d0;
    const float* xb = xbar + h * 512 + fq * 128;
    float acc[8];
#pragma unroll
    for (int k = 0; k < 8; ++k) acc[k] = 0.f;
#pragma unroll 4
    for (int i = 0; i < 128; ++i) {
        float wv[8];
        load8(wp + (size_t)(fq * 128 + i) * 128, wv);
        float xv = xb[i];
#pragma unroll
        for (int k = 0; k < 8; ++k) acc[k] += xv * wv[k];
    }
    float* r = red + ((size_t)fq * 64 + cb) * 8;
    *(float4*)(r + 0) = make_float4(acc[0], acc[1], acc[2], acc[3]);
    *(float4*)(r + 4) = make_float4(acc[4], acc[5], acc[6], acc[7]);
    __syncthreads();
    if (tid < 64) {
        float s[8] = {0.f,0.f,0.f,0.f,0.f,0.f,0.f,0.f};
#pragma unroll
        for (int q = 0; q < 4; ++q) {
            const float* rr = red + ((size_t)q * 64 + tid) * 8;
            float4 p0 = *(const float4*)rr;
            float4 p1 = *(const float4*)(rr + 4);
            s[0] += p0.x; s[1] += p0.y; s[2] += p0.z; s[3] += p0.w;
            s[4] += p1.x; s[5] += p1.y; s[6] += p1.z; s[7] += p1.w;
        }
        float* o = hroot + tid * 8;
        *(float4*)(o + 0) = make_float4(s[0], s[1], s[2], s[3]);
        *(float4*)(o + 4) = make_float4(s[4], s[5], s[6], s[7]);
    }
    __syncthreads();
}

template <typename T>
__device__ __forceinline__ void projection2(const float* hroot, const T* fcw,
                                            T* outp, float* red, int tid) {
    const int fq = tid >> 5;
    const int jb = tid & 31;
    const int j0 = jb * 8;
    float acc[8];
#pragma unroll
    for (int k = 0; k < 8; ++k) acc[k] = 0.f;
#pragma unroll 4
    for (int i = 0; i < 64; ++i) {
        int f = fq * 64 + i;
        float wv[8];
        load8(fcw + (size_t)f * 256 + j0, wv);
        float xv = hroot[f];
#pragma unroll
        for (int k = 0; k < 8; ++k) acc[k] += xv * wv[k];
    }
    float* r = red + ((size_t)fq * 32 + jb) * 8;
    *(float4*)(r + 0) = make_float4(acc[0], acc[1], acc[2], acc[3]);
    *(float4*)(r + 4) = make_float4(acc[4], acc[5], acc[6], acc[7]);
    __syncthreads();
    if (tid < 32) {
        float s[8] = {0.f,0.f,0.f,0.f,0.f,0.f,0.f,0.f};
#pragma unroll
        for (int q = 0; q < 8; ++q) {
            const float* rr = red + ((size_t)q * 32 + tid) * 8;
            float4 p0 = *(const float4*)rr;
            float4 p1 = *(const float4*)(rr + 4);
            s[0] += p0.x; s[1] += p0.y; s[2] += p0.z; s[3] += p0.w;
            s[4] += p1.x; s[5] += p1.y; s[6] += p1.z; s[7] += p1.w;
        }
#pragma unroll
        for (int k = 0; k < 8; ++k) store_val(outp + tid * 8 + k, s[k]);
    }
}

template <typename T, int G>
__device__ __forceinline__ void l0_body2(
    const T* x0, const T* x1, const T* x2, const T* w0, const T* a0s,
    const T* a0n, float* wsout, float* xs, float* xbar, float (*attnT)[4],
    float* part, int b0, int node, int tid)
{
    for (int g = 0; g < G; ++g) {
        int b = b0 + g;
        if (node == 0) {
            stage<T, 256, 11, 260>(xs, x0 + (size_t)b * 256, x1 + (size_t)b * 2560, tid);
            __syncthreads();
            attention2<T, 256, 11, 260>(xs, a0s, a0n, attnT, part, tid);
            aggregate2<256, 11, 260>(xs, attnT, xbar + g * 1028, tid);
        } else {
            int p = node - 1;
            stage<T, 256, 26, 260>(xs, x1 + ((size_t)b * 10 + p) * 256,
                                   x2 + ((size_t)b * 250 + (size_t)p * 25) * 256, tid);
            __syncthreads();
            attention2<T, 256, 26, 260>(xs, a0s, a0n, attnT, part, tid);
            aggregate2<256, 26, 260>(xs, attnT, xbar + g * 1028, tid);
        }
        __syncthreads();
    }
    transformA<T, G>(xbar, w0, wsout, b0, node, tid);
}

template <int G>
__global__ __launch_bounds__(256) void gat_l0(
    const void* x0, const void* x1, const void* x2, const void* w0,
    const void* a0s, const void* a0n, float* ws)
{
    const int node = blockIdx.x % 11;
    const int b0 = (blockIdx.x / 11) * G;
    const int tid = threadIdx.x;
    __shared__ __align__(16) float xs[26 * 260];
    __shared__ __align__(16) float xbar[4 * 1028];
    __shared__ __align__(16) float attnT[26][4];
    __shared__ float part[256];
    __shared__ int is_fp32;
    if (detect_fp32(x0, tid, &is_fp32))
        l0_body2<float, G>((const float*)x0, (const float*)x1, (const float*)x2,
                           (const float*)w0, (const float*)a0s, (const float*)a0n,
                           ws, xs, xbar, attnT, part, b0, node, tid);
    else
        l0_body2<bf16, G>((const bf16*)x0, (const bf16*)x1, (const bf16*)x2,
                          (const bf16*)w0, (const bf16*)a0s, (const bf16*)a0n,
                          ws, xs, xbar, attnT, part, b0, node, tid);
}

template <typename T>
__device__ __forceinline__ void root_body2(
    const float* wsin, const T* w1, const T* a1s, const T* a1n, const T* fcw,
    T* out, float* hs, float* xbar, float* hroot, float (*attnT)[4],
    float* part, int b, int tid)
{
    for (int i = tid; i < 11 * 128; i += 256) {
        int e = i * 4;
        int s = e >> 9, f = e & 511;
        float4 v = *(const float4*)(wsin + ((size_t)b * 11 + s) * 512 + f);
        *(float4*)&hs[s * 516 + f] = v;
    }
    __syncthreads();
    attention2<T, 512, 11, 516>(hs, a1s, a1n, attnT, part, tid);
    aggregate2<512, 11, 516>(hs, attnT, xbar, tid);
    __syncthreads();
    transformR<T>(xbar, w1, hs, hroot, tid);
    projection2<T>(hroot, fcw, out + (size_t)b * 256, hs, tid);
}

__global__ __launch_bounds__(256) void gat_root(
    const void* x0, const float* ws, const void* w1, const void* a1s,
    const void* a1n, const void* fcw, void* out)
{
    const int b = blockIdx.x;
    const int tid = threadIdx.x;
    __shared__ __align__(16) float hs[11 * 516];
    __shared__ __align__(16) float xbar[4 * 512];
    __shared__ __align__(16) float hroot[512];
    __shared__ __align__(16) float attnT[26][4];
    __shared__ float part[256];
    __shared__ int is_fp32;
    if (detect_fp32(x0, tid, &is_fp32))
        root_body2<float>(ws, (const float*)w1, (const float*)a1s,
                          (const float*)a1n, (const float*)fcw, (float*)out,
                          hs, xbar, hroot, attnT, part, b, tid);
    else
        root_body2<bf16>(ws, (const bf16*)w1, (const bf16*)a1s,
                         (const bf16*)a1n, (const bf16*)fcw, (bf16*)out,
                         hs, xbar, hroot, attnT, part, b, tid);
}

// ================= Last-resort fallback: fully-fused ========================
template <typename T, int F>
__device__ __forceinline__ void transform_o(const float* xbar, const T* w,
                                            float* dst, int tid) {
#pragma unroll
    for (int r = 0; r < 2; ++r) {
        int o = tid + r * 256;
        int h = o >> 7, d = o & 127;
        const T* wp = w + (size_t)h * F * 128 + d;
        const float* xb = xbar + (size_t)h * F;
        float a0 = 0.f, a1 = 0.f, a2 = 0.f, a3 = 0.f;
        for (int f = 0; f < F; f += 4) {
            a0 += xb[f + 0] * tof(wp[(size_t)(f + 0) * 128]);
            a1 += xb[f + 1] * tof(wp[(size_t)(f + 1) * 128]);
            a2 += xb[f + 2] * tof(wp[(size_t)(f + 2) * 128]);
            a3 += xb[f + 3] * tof(wp[(size_t)(f + 3) * 128]);
        }
        dst[o] = (a0 + a1) + (a2 + a3);
    }
}

template <typename T>
__device__ __forceinline__ void gat_body_fb(
    const T* x0, const T* x1, const T* x2, const T* w0, const T* a0s,
    const T* a0n, const T* w1, const T* a1s, const T* a1n, const T* fcw,
    T* out, float* xs, float* hs, float* xbar, float (*attnT)[4],
    float* part, float* hroot, int b, int tid)
{
    for (int p = 0; p < 10; ++p) {
        stage<T, 256, 26, 260>(xs, x1 + ((size_t)b * 10 + p) * 256,
                               x2 + ((size_t)b * 250 + (size_t)p * 25) * 256, tid);
        __syncthreads();
        attention2<T, 256, 26, 260>(xs, a0s, a0n, attnT, part, tid);
        aggregate2<256, 26, 260>(xs, attnT, xbar, tid);
        __syncthreads();
        transform_o<T, 256>(xbar, w0, &hs[(p + 1) * 516], tid);
        __syncthreads();
    }
    stage<T, 256, 11, 260>(xs, x0 + (size_t)b * 256, x1 + (size_t)b * 2560, tid);
    __syncthreads();
    attention2<T, 256, 11, 260>(xs, a0s, a0n, attnT, part, tid);
    aggregate2<256, 11, 260>(xs, attnT, xbar, tid);
    __syncthreads();
    transform_o<T, 256>(xbar, w0, &hs[0], tid);
    __syncthreads();
    attention2<T, 512, 11, 516>(hs, a1s, a1n, attnT, part, tid);
    aggregate2<512, 11, 516>(hs, attnT, xbar, tid);
    __syncthreads();
    transform_o<T, 512>(xbar, w1, hroot, tid);
    __syncthreads();
    const T* fp = fcw + tid;
    float a0 = 0.f, a1 = 0.f, a2 = 0.f, a3 = 0.f;
    for (int f = 0; f < 512; f += 4) {
        a0 += hroot[f + 0] * tof(fp[(size_t)(f + 0) * 256]);
        a1 += hroot[f + 1] * tof(fp[(size_t)(f + 1) * 256]);
        a2 += hroot[f + 2] * tof(fp[(size_t)(f + 2) * 256]);
        a3 += hroot[f + 3] * tof(fp[(size_t)(f + 3) * 256]);
    }
    store_val(&out[(size_t)b * 256 + tid], (a0 + a1) + (a2 + a3));
}

__global__ __launch_bounds__(256) void gat_fused(
    const void* x0, const void* x1, const void* x2, const void* w0,
    const void* a0s, const void* a0n, const void* w1, const void* a1s,
    const void* a1n, const void* fcw, void* out)
{
    const int b = blockIdx.x;
    const int tid = threadIdx.x;
    __shared__ __align__(16) float xs[26 * 260];
    __shared__ __align__(16) float hs[11 * 516];
    __shared__ __align__(16) float xbar[4 * 512];
    __shared__ __align__(16) float attnT[26][4];
    __shared__ float part[256];
    __shared__ __align__(16) float hroot[512];
    __shared__ int is_fp32;
    if (detect_fp32(x0, tid, &is_fp32))
        gat_body_fb<float>((const float*)x0, (const float*)x1, (const float*)x2,
                           (const float*)w0, (const float*)a0s, (const float*)a0n,
                           (const float*)w1, (const float*)a1s, (const float*)a1n,
                           (const float*)fcw, (float*)out,
                           xs, hs, xbar, attnT, part, hroot, b, tid);
    else
        gat_body_fb<bf16>((const bf16*)x0, (const bf16*)x1, (const bf16*)x2,
                          (const bf16*)w0, (const bf16*)a0s, (const bf16*)a0n,
                          (const bf16*)w1, (const bf16*)a1s, (const bf16*)a1n,
                          (const bf16*)fcw, (bf16*)out,
                          xs, hs, xbar, attnT, part, hroot, b, tid);
}

extern "C" void kernel_launch(void* const* d_in, const int* in_sizes, int n_in,
                              void* d_out, int out_size, void* d_ws, size_t ws_size,
                              hipStream_t stream) {
    const int B = in_sizes[0] / 256;  // 1024
    // ws layout (floats): xbar0[B*11*1024] | hs[B*11*512] | xbar1[B*2048] | hroot[B*512]
    const size_t ws_need5 = (size_t)B * 19456 * sizeof(float);       // ~79.7 MB @ B=1024
    const size_t ws_need2 = (size_t)B * 11 * 512 * sizeof(float);    // ~23.1 MB

    if (d_ws && ws_size >= ws_need5 && (B % 64) == 0) {
        float* xbar0 = (float*)d_ws;
        float* hsws  = xbar0 + (size_t)B * 11 * 1024;
        float* xbar1 = hsws  + (size_t)B * 11 * 512;
        float* hroot = xbar1 + (size_t)B * 2048;

        gat_agg0<<<B * 11, 256, 0, stream>>>(d_in[0], d_in[1], d_in[2],
                                             d_in[4], d_in[5], xbar0);
        // level-0 transform: M=B*11, K=256, N=128 x 4 heads
        gat_gemm<64, 256, 1024, 256, 256 * 128, 128, 512, 128, 4, false>
            <<<(B * 11 / 64) * 4, 256, 0, stream>>>(d_in[0], xbar0, d_in[3], hsws);
        gat_agg1<<<B, 256, 0, stream>>>(d_in[0], hsws, d_in[7], d_in[8], xbar1);
        // root transform: M=B, K=512, N=128 x 4 heads
        gat_gemm<32, 512, 2048, 512, 512 * 128, 128, 512, 128, 4, false>
            <<<(B / 32) * 4, 256, 0, stream>>>(d_in[0], xbar1, d_in[6], hroot);
        // projection: M=B, K=512, N=256 as 2 column-tiles
        gat_gemm<32, 512, 512, 0, 128, 256, 256, 128, 2, true>
            <<<(B / 32) * 2, 256, 0, stream>>>(d_in[0], hroot, d_in[9], d_out);
    } else if (d_ws && ws_size >= ws_need2 && (B % 4) == 0) {
        float* ws = (float*)d_ws;
        gat_l0<4><<<(B / 4) * 11, 256, 0, stream>>>(
            d_in[0], d_in[1], d_in[2], d_in[3], d_in[4], d_in[5], ws);
        gat_root<<<B, 256, 0, stream>>>(
            d_in[0], ws, d_in[6], d_in[7], d_in[8], d_in[9], d_out);
    } else {
        gat_fused<<<B, 256, 0, stream>>>(d_in[0], d_in[1], d_in[2], d_in[3],
                                         d_in[4], d_in[5], d_in[6], d_in[7],
                                         d_in[8], d_in[9], d_out);
    }
}